// Round 2
// baseline (846.388 us; speedup 1.0000x reference)
//
#include <hip/hip_runtime.h>
#include <hip/hip_bf16.h>
#include <math.h>

// TriangleMultiplicativeUpdate (outgoing), B=1 N=512 C_Z=C_H=128, fp32 in/out.
// R3: decouple LN from projections.
//   - k_ln: z fp32 -> zn bf16 (plain normalized; affine folded into weights/biases
//     by k_wt_all/k_bias). Pure streaming, BW-bound.
//   - k_proj2: reads zn tile into LDS (1 barrier), 5 MFMA projections + gating,
//     per-wave output staging. No shuffles, no float4[8] hump -> VGPR<=128
//     (__launch_bounds__(256,4)) for 4 blocks/CU.
//   - zn aliases x_t workspace (dead until k_tri writes it).
//   - k_tri reverted to R1 exactly (R2's prefetch+swizzle regressed ~90us).

#define N 512
#define C 128
#define NN (N*N)
#define PK 136   // padded LDS stride (u16) for MFMA A tiles
#define PT 40    // padded LDS stride for K=32 bf16 tiles (k_tri)
#define PX 137   // padded LDS stride for fp32 x-tile transpose (k_out)
#define ST 72    // per-channel stride (u16) in per-wave transpose buffer

typedef __attribute__((ext_vector_type(8))) short bf16x8;
typedef __attribute__((ext_vector_type(4))) float f32x4;
typedef unsigned short u16;
typedef unsigned int u32;

__device__ __forceinline__ u16 f2bf(float f) {
    u32 u = __builtin_bit_cast(u32, f);
    u = (u + 0x7fffu + ((u >> 16) & 1u)) >> 16;
    return (u16)u;
}
__device__ __forceinline__ float bf2f(u16 h) {
    return __builtin_bit_cast(float, ((u32)h) << 16);
}
__device__ __forceinline__ float sigmoidf(float x) {
    return 1.f / (1.f + __expf(-x));
}

// ------- K0: weights fp32 [in][out] -> bf16 transposed, LN gain folded in ----
__global__ __launch_bounds__(256) void k_wt_all(
    const float* __restrict__ w0, const float* __restrict__ w1,
    const float* __restrict__ w2, const float* __restrict__ w3,
    const float* __restrict__ w4, const float* __restrict__ w5,
    const float* __restrict__ gin, const float* __restrict__ gout,
    u16* __restrict__ o0, u16* __restrict__ o1, u16* __restrict__ o2,
    u16* __restrict__ o3, u16* __restrict__ o4, u16* __restrict__ o5) {
    int sel = blockIdx.x >> 6;
    int idx = (blockIdx.x & 63) * 256 + threadIdx.x;
    const float* w = sel == 0 ? w0 : sel == 1 ? w1 : sel == 2 ? w2
                   : sel == 3 ? w3 : sel == 4 ? w4 : w5;
    u16* o = sel == 0 ? o0 : sel == 1 ? o1 : sel == 2 ? o2
           : sel == 3 ? o3 : sel == 4 ? o4 : o5;
    const float* g = (sel == 5) ? gout : gin;
    int co = idx >> 7, k = idx & 127;
    o[idx] = f2bf(g[k] * w[k * C + co]);
}

// ------- K0b: adjusted biases  b'[c] = b[c] + sum_k b_ln[k]*W[k][c] ----------
__global__ __launch_bounds__(256) void k_bias(
    const float* __restrict__ w0, const float* __restrict__ w1,
    const float* __restrict__ w2, const float* __restrict__ w3,
    const float* __restrict__ w4, const float* __restrict__ w5,
    const float* __restrict__ b0, const float* __restrict__ b1,
    const float* __restrict__ b2, const float* __restrict__ b3,
    const float* __restrict__ b4, const float* __restrict__ b5,
    const float* __restrict__ vin, const float* __restrict__ vout,
    float* __restrict__ obias) {
    int id = blockIdx.x * 256 + threadIdx.x;   // 0..767
    int m = id >> 7, cc = id & 127;
    const float* w = m == 0 ? w0 : m == 1 ? w1 : m == 2 ? w2
                   : m == 3 ? w3 : m == 4 ? w4 : w5;
    const float* b = m == 0 ? b0 : m == 1 ? b1 : m == 2 ? b2
                   : m == 3 ? b3 : m == 4 ? b4 : b5;
    const float* v = (m == 5) ? vout : vin;
    float acc = 0.f;
#pragma unroll 4
    for (int k = 0; k < 128; ++k) acc += v[k] * w[k * C + cc];
    obias[id] = b[cc] + acc;
}

// ------- K1: LN(z) -> zn bf16 (plain normalized), pure streaming -------------
__global__ __launch_bounds__(256) void k_ln(const float* __restrict__ z,
                                            u16* __restrict__ zn) {
    long gid = (long)blockIdx.x * 256 + threadIdx.x;
    long row = gid >> 2;          // 4 lanes per row
    int cb = (int)(gid & 3);      // 32 cols each
    const float* zr = z + row * C + cb * 32;
    float4 v[8];
    float s = 0.f, s2 = 0.f;
#pragma unroll
    for (int i = 0; i < 8; ++i) {
        v[i] = *(const float4*)(zr + i * 4);
        s  += v[i].x + v[i].y + v[i].z + v[i].w;
        s2 += v[i].x * v[i].x + v[i].y * v[i].y + v[i].z * v[i].z + v[i].w * v[i].w;
    }
    s += __shfl_xor(s, 1); s2 += __shfl_xor(s2, 1);
    s += __shfl_xor(s, 2); s2 += __shfl_xor(s2, 2);
    float mean = s * (1.f / 128.f);
    float rs = rsqrtf(s2 * (1.f / 128.f) - mean * mean + 1e-5f);
    u16* dst = zn + row * C + cb * 32;
#pragma unroll
    for (int j = 0; j < 4; ++j) {
        uint4 pk;
        pk.x = (u32)f2bf((v[2*j].x   - mean) * rs) | ((u32)f2bf((v[2*j].y   - mean) * rs) << 16);
        pk.y = (u32)f2bf((v[2*j].z   - mean) * rs) | ((u32)f2bf((v[2*j].w   - mean) * rs) << 16);
        pk.z = (u32)f2bf((v[2*j+1].x - mean) * rs) | ((u32)f2bf((v[2*j+1].y - mean) * rs) << 16);
        pk.w = (u32)f2bf((v[2*j+1].z - mean) * rs) | ((u32)f2bf((v[2*j+1].w - mean) * rs) << 16);
        *(uint4*)(dst + 8 * j) = pk;
    }
}

// ------- K2: projections + gating from pre-normalized zn ---------------------
// block = 256 threads, 64 rows. Wave w owns output cols [w*32, w*32+32).
__global__ __launch_bounds__(256, 4) void k_proj2(
    const u16* __restrict__ zn, const float* __restrict__ mask,
    const u16* __restrict__ wag, const u16* __restrict__ wap,
    const u16* __restrict__ wbg, const u16* __restrict__ wbp,
    const u16* __restrict__ wgg, const float* __restrict__ biasAll,
    u16* __restrict__ aT, u16* __restrict__ bT, u16* __restrict__ gate) {
    __shared__ u16 sA[64 * PK];        // 17408 B
    __shared__ u16 sT[4][16 * ST];     //  9216 B, per-wave private 16ch x 64row
    long r0 = (long)blockIdx.x * 64;
    int tid = threadIdx.x, wave = tid >> 6, lane = tid & 63;
    int lo = lane & 15, quad = lane >> 4;

    // --- fill sA with zn tile (padded rows, conflict-free fragment reads) ---
#pragma unroll
    for (int p = 0; p < 4; ++p) {
        int linear = p * 2048 + tid * 8;
        int row = linear >> 7, k = linear & 127;
        *(uint4*)(&sA[row * PK + k]) = *(const uint4*)(zn + (r0 + row) * C + k);
    }
    __syncthreads();

    int c0 = wave * 32;
    float msk[4][4];
#pragma unroll
    for (int mi = 0; mi < 4; ++mi)
#pragma unroll
        for (int r = 0; r < 4; ++r)
            msk[mi][r] = mask[r0 + mi * 16 + quad * 4 + r];

    u16* sTw = &sT[wave][0];

    // --- gated pair: outT[c][r] = mask*sigmoid(zn@wG+bG')*(zn@wP+bP') --------
    auto pair_stage = [&](const u16* __restrict__ wG, const float* __restrict__ bG,
                          const u16* __restrict__ wP, const float* __restrict__ bP,
                          u16* __restrict__ outT) {
#pragma unroll
        for (int nt = 0; nt < 2; ++nt) {
            int c = c0 + nt * 16 + lo;
            bf16x8 fG[4], fP[4];
#pragma unroll
            for (int ki = 0; ki < 4; ++ki) {
                fG[ki] = *(const bf16x8*)(wG + c * C + ki * 32 + quad * 8);
                fP[ki] = *(const bf16x8*)(wP + c * C + ki * 32 + quad * 8);
            }
            f32x4 aG[4], aP[4];
#pragma unroll
            for (int mi = 0; mi < 4; ++mi) { aG[mi] = (f32x4)(0.f); aP[mi] = (f32x4)(0.f); }
#pragma unroll
            for (int mi = 0; mi < 4; ++mi)
#pragma unroll
                for (int ki = 0; ki < 4; ++ki) {
                    bf16x8 av = *(const bf16x8*)(&sA[(mi * 16 + lo) * PK + ki * 32 + quad * 8]);
                    aG[mi] = __builtin_amdgcn_mfma_f32_16x16x32_bf16(av, fG[ki], aG[mi], 0, 0, 0);
                    aP[mi] = __builtin_amdgcn_mfma_f32_16x16x32_bf16(av, fP[ki], aP[mi], 0, 0, 0);
                }
            float bGv = bG[c], bPv = bP[c];
#pragma unroll
            for (int mi = 0; mi < 4; ++mi) {
                float v0 = msk[mi][0] * sigmoidf(aG[mi][0] + bGv) * (aP[mi][0] + bPv);
                float v1 = msk[mi][1] * sigmoidf(aG[mi][1] + bGv) * (aP[mi][1] + bPv);
                float v2 = msk[mi][2] * sigmoidf(aG[mi][2] + bGv) * (aP[mi][2] + bPv);
                float v3 = msk[mi][3] * sigmoidf(aG[mi][3] + bGv) * (aP[mi][3] + bPv);
                uint2 pk;
                pk.x = (u32)f2bf(v0) | ((u32)f2bf(v1) << 16);
                pk.y = (u32)f2bf(v2) | ((u32)f2bf(v3) << 16);
                *(uint2*)(&sTw[lo * ST + mi * 16 + quad * 4]) = pk;
            }
            // per-wave copy out: 16 ch x 64 rows, no barrier needed (wave-private)
            {
                int cl = lane >> 2, pr = lane & 3;
                uint4 x0 = *(const uint4*)(&sTw[cl * ST + pr * 16]);
                uint4 x1 = *(const uint4*)(&sTw[cl * ST + pr * 16 + 8]);
                u16* g = outT + (long)(c0 + nt * 16 + cl) * NN + r0 + pr * 16;
                *(uint4*)(g) = x0;
                *(uint4*)(g + 8) = x1;
            }
        }
    };
    pair_stage(wag, biasAll + 0,   wap, biasAll + 128, aT);
    pair_stage(wbg, biasAll + 256, wbp, biasAll + 384, bT);

    // --- gate: gate[r][c] = sigmoid(zn@w_g + b_g') ---------------------------
    {
        f32x4 gA[2][4];
#pragma unroll
        for (int nt = 0; nt < 2; ++nt) {
            bf16x8 gF[4];
#pragma unroll
            for (int ki = 0; ki < 4; ++ki)
                gF[ki] = *(const bf16x8*)(wgg + (c0 + nt * 16 + lo) * C + ki * 32 + quad * 8);
#pragma unroll
            for (int mi = 0; mi < 4; ++mi) gA[nt][mi] = (f32x4)(0.f);
#pragma unroll
            for (int mi = 0; mi < 4; ++mi)
#pragma unroll
                for (int ki = 0; ki < 4; ++ki) {
                    bf16x8 av = *(const bf16x8*)(&sA[(mi * 16 + lo) * PK + ki * 32 + quad * 8]);
                    gA[nt][mi] = __builtin_amdgcn_mfma_f32_16x16x32_bf16(av, gF[ki], gA[nt][mi], 0, 0, 0);
                }
        }
        __syncthreads();   // all waves done reading sA before overwrite
        const float* bg5 = biasAll + 512;
#pragma unroll
        for (int nt = 0; nt < 2; ++nt) {
            int c = c0 + nt * 16 + lo;
            float bv = bg5[c];
#pragma unroll
            for (int mi = 0; mi < 4; ++mi)
#pragma unroll
                for (int r = 0; r < 4; ++r)
                    sA[(mi * 16 + quad * 4 + r) * PK + c] = f2bf(sigmoidf(gA[nt][mi][r] + bv));
        }
        __syncthreads();
#pragma unroll
        for (int p = 0; p < 4; ++p) {
            int linear = p * 2048 + tid * 8;
            int row = linear >> 7, k = linear & 127;
            *(uint4*)(gate + (r0 + row) * C + k) = *(const uint4*)(&sA[row * PK + k]);
        }
    }
}

// ------- K3: per-channel 512x512x512 BT-GEMM (R1 form) -----------------------
// x_t[c][i][j] = sum_k a_t[c][i][k] * b_t[c][j][k]
__global__ __launch_bounds__(256) void k_tri(const u16* __restrict__ aT,
                                             const u16* __restrict__ bT,
                                             u16* __restrict__ xT) {
    __shared__ u16 sA[128 * PT];
    __shared__ u16 sB[128 * PT];
    int c = blockIdx.y;
    int i0 = (blockIdx.x >> 2) * 128, j0 = (blockIdx.x & 3) * 128;
    const u16* aBase = aT + (long)c * NN + (long)i0 * N;
    const u16* bBase = bT + (long)c * NN + (long)j0 * N;
    int tid = threadIdx.x;
    int wave = tid >> 6, lane = tid & 63, lo = lane & 15, quad = lane >> 4;
    int mq = (wave >> 1) * 64, nq = (wave & 1) * 64;
    f32x4 acc[4][4];
#pragma unroll
    for (int mi = 0; mi < 4; ++mi)
#pragma unroll
        for (int ni = 0; ni < 4; ++ni) acc[mi][ni] = (f32x4)(0.f);
    for (int kk = 0; kk < N; kk += 32) {
        __syncthreads();
#pragma unroll
        for (int p = 0; p < 2; ++p) {
            int linear = p * 2048 + tid * 8;
            int row = linear >> 5, k = linear & 31;
            *(uint4*)(&sA[row * PT + k]) = *(const uint4*)(aBase + row * N + kk + k);
            *(uint4*)(&sB[row * PT + k]) = *(const uint4*)(bBase + row * N + kk + k);
        }
        __syncthreads();
        bf16x8 af[4], bfr[4];
#pragma unroll
        for (int mi = 0; mi < 4; ++mi)
            af[mi] = *(const bf16x8*)(&sA[(mq + mi * 16 + lo) * PT + quad * 8]);
#pragma unroll
        for (int ni = 0; ni < 4; ++ni)
            bfr[ni] = *(const bf16x8*)(&sB[(nq + ni * 16 + lo) * PT + quad * 8]);
#pragma unroll
        for (int mi = 0; mi < 4; ++mi)
#pragma unroll
            for (int ni = 0; ni < 4; ++ni)
                acc[mi][ni] = __builtin_amdgcn_mfma_f32_16x16x32_bf16(af[mi], bfr[ni], acc[mi][ni], 0, 0, 0);
    }
    u16* outBase = xT + (long)c * NN;
#pragma unroll
    for (int mi = 0; mi < 4; ++mi)
#pragma unroll
        for (int ni = 0; ni < 4; ++ni)
#pragma unroll
            for (int r = 0; r < 4; ++r) {
                int gi = i0 + mq + mi * 16 + quad * 4 + r;
                int gj = j0 + nq + ni * 16 + lo;
                outBase[(long)gi * N + gj] = f2bf(acc[mi][ni][r]);
            }
}

// ------- K4: LN(x) @ w_z' + b_z', * gate -> out fp32 (ln_out folded) ---------
__global__ __launch_bounds__(256) void k_out(
    const u16* __restrict__ xT, const u16* __restrict__ gate,
    const u16* __restrict__ wzT, const float* __restrict__ bz,
    float* __restrict__ out) {
    __shared__ float sX[64 * PX];
    __shared__ u16 sA[64 * PK];
    __shared__ float sRed[2][4][64];
    __shared__ float2 sMV[64];
    long r0 = (long)blockIdx.x * 64;
    int tid = threadIdx.x;
#pragma unroll
    for (int p = 0; p < 4; ++p) {
        int linear = p * 2048 + tid * 8;
        int cc = linear >> 6, jr = linear & 63;
        uint4 v = *(const uint4*)(xT + (long)cc * NN + r0 + jr);
        u16* u = (u16*)&v;
#pragma unroll
        for (int e = 0; e < 8; ++e) sX[(jr + e) * PX + cc] = bf2f(u[e]);
    }
    __syncthreads();
    {
        int jr = tid & 63, part = tid >> 6;
        float s = 0, s2 = 0;
#pragma unroll
        for (int c = part * 32; c < part * 32 + 32; ++c) {
            float v = sX[jr * PX + c];
            s += v; s2 += v * v;
        }
        sRed[0][part][jr] = s; sRed[1][part][jr] = s2;
    }
    __syncthreads();
    if (tid < 64) {
        float S = 0, S2 = 0;
#pragma unroll
        for (int p = 0; p < 4; ++p) { S += sRed[0][p][tid]; S2 += sRed[1][p][tid]; }
        float mean = S * (1.f / 128.f);
        float var = S2 * (1.f / 128.f) - mean * mean;
        sMV[tid] = make_float2(mean, rsqrtf(var + 1e-5f));
    }
    __syncthreads();
    {
        int row = tid & 63, c0 = (tid >> 6) * 32;
        float2 mv = sMV[row];
#pragma unroll
        for (int c = c0; c < c0 + 32; ++c)
            sA[row * PK + c] = f2bf((sX[row * PX + c] - mv.x) * mv.y);
    }
    __syncthreads();
    int wave = tid >> 6, lane = tid & 63, lo = lane & 15, quad = lane >> 4;
    int msub = wave * 16;
    bf16x8 av[4];
#pragma unroll
    for (int ki = 0; ki < 4; ++ki)
        av[ki] = *(const bf16x8*)(&sA[(msub + lo) * PK + ki * 32 + quad * 8]);
    f32x4 acc[8];
#pragma unroll
    for (int nt = 0; nt < 8; ++nt) acc[nt] = (f32x4)(0.f);
#pragma unroll
    for (int nt = 0; nt < 8; ++nt)
#pragma unroll
        for (int ki = 0; ki < 4; ++ki) {
            bf16x8 b8 = *(const bf16x8*)(wzT + (nt * 16 + lo) * C + ki * 32 + quad * 8);
            acc[nt] = __builtin_amdgcn_mfma_f32_16x16x32_bf16(av[ki], b8, acc[nt], 0, 0, 0);
        }
#pragma unroll
    for (int nt = 0; nt < 8; ++nt) {
        int c = nt * 16 + lo;
        float bzv = bz[c];
#pragma unroll
        for (int r = 0; r < 4; ++r) {
            int row = msub + quad * 4 + r;
            long rr = r0 + row;
            float g = bf2f(gate[rr * C + c]);
            out[rr * C + c] = (acc[nt][r] + bzv) * g;
        }
    }
}

extern "C" void kernel_launch(void* const* d_in, const int* in_sizes, int n_in,
                              void* d_out, int out_size, void* d_ws, size_t ws_size,
                              hipStream_t stream) {
    const float* z       = (const float*)d_in[0];
    const float* mask    = (const float*)d_in[1];
    const float* w_ag    = (const float*)d_in[2];
    const float* b_ag    = (const float*)d_in[3];
    const float* w_ap    = (const float*)d_in[4];
    const float* b_ap    = (const float*)d_in[5];
    const float* w_bg    = (const float*)d_in[6];
    const float* b_bg    = (const float*)d_in[7];
    const float* w_bp    = (const float*)d_in[8];
    const float* b_bp    = (const float*)d_in[9];
    const float* w_g     = (const float*)d_in[10];
    const float* b_g     = (const float*)d_in[11];
    const float* w_z     = (const float*)d_in[12];
    const float* b_z     = (const float*)d_in[13];
    const float* ln_in_g = (const float*)d_in[14];
    const float* ln_in_b = (const float*)d_in[15];
    const float* ln_out_g= (const float*)d_in[16];
    const float* ln_out_b= (const float*)d_in[17];
    float* out = (float*)d_out;

    char* ws = (char*)d_ws;
    u16* a_t  = (u16*)(ws);                          // 64 MB
    u16* b_t  = (u16*)(ws + 67108864L);              // 64 MB
    u16* gate = (u16*)(ws + 134217728L);             // 64 MB
    u16* x_t  = (u16*)(ws + 201326592L);             // 64 MB (aliased as zn pre-k_tri)
    u16* wag_t = (u16*)(ws + 268435456L);
    u16* wap_t = wag_t + 16384;
    u16* wbg_t = wag_t + 32768;
    u16* wbp_t = wag_t + 49152;
    u16* wg_t  = wag_t + 65536;
    u16* wz_t  = wag_t + 81920;
    float* biasAdj = (float*)(ws + 268435456L + 196608L);   // 6*128 fp32
    u16* zn = x_t;   // zn dead before k_tri writes x_t (same stream, in-order)

    k_wt_all<<<384, 256, 0, stream>>>(w_ag, w_ap, w_bg, w_bp, w_g, w_z,
                                      ln_in_g, ln_out_g,
                                      wag_t, wap_t, wbg_t, wbp_t, wg_t, wz_t);

    k_bias<<<3, 256, 0, stream>>>(w_ag, w_ap, w_bg, w_bp, w_g, w_z,
                                  b_ag, b_ap, b_bg, b_bp, b_g, b_z,
                                  ln_in_b, ln_out_b, biasAdj);

    k_ln<<<4096, 256, 0, stream>>>(z, zn);

    k_proj2<<<NN / 64, 256, 0, stream>>>(
        zn, mask, wag_t, wap_t, wbg_t, wbp_t, wg_t, biasAdj,
        a_t, b_t, gate);

    k_tri<<<dim3(16, 128), 256, 0, stream>>>(a_t, b_t, x_t);

    k_out<<<NN / 64, 256, 0, stream>>>(x_t, gate, wz_t, biasAdj + 640, out);
}

// Round 3
// 579.349 us; speedup vs baseline: 1.4609x; 1.4609x over previous
//
#include <hip/hip_runtime.h>
#include <hip/hip_bf16.h>
#include <math.h>

// TriangleMultiplicativeUpdate (outgoing), B=1 N=512 C_Z=C_H=128, fp32 in/out.
// R4: revert to the fused-k_proj structure (R2 form, measured 215us; R3's
//     decoupled LN caused a 1.8GB traffic blowup -> reverted).
//     k_tri: R1 mapping (natural dispatch, no swizzle, no reg-prefetch) with
//     ONE isolated change: global_load_lds width-16 staging into linear
//     [128][32] LDS (async DMA, no VGPR round-trip, 16KB LDS, bank-balanced
//     fragment reads). Everything else byte-identical to the measured-good R2.

#define N 512
#define C 128
#define NN (N*N)
#define PK 136   // padded LDS stride (u16) for MFMA A tiles
#define PX 137   // padded LDS stride for fp32 x-tile transpose (k_out)
#define ST 72    // per-channel stride (u16) in per-wave transpose buffer

typedef __attribute__((ext_vector_type(8))) short bf16x8;
typedef __attribute__((ext_vector_type(4))) float f32x4;
typedef unsigned short u16;
typedef unsigned int u32;

__device__ __forceinline__ u16 f2bf(float f) {
    u32 u = __builtin_bit_cast(u32, f);
    u = (u + 0x7fffu + ((u >> 16) & 1u)) >> 16;
    return (u16)u;
}
__device__ __forceinline__ float bf2f(u16 h) {
    return __builtin_bit_cast(float, ((u32)h) << 16);
}
__device__ __forceinline__ float sigmoidf(float x) {
    return 1.f / (1.f + __expf(-x));
}
// async global->LDS, 16B per lane; lds dest must be wave-uniform (HW adds lane*16)
__device__ __forceinline__ void gload16(const u16* g, u16* lds) {
    __builtin_amdgcn_global_load_lds(
        (const __attribute__((address_space(1))) unsigned int*)g,
        (__attribute__((address_space(3))) unsigned int*)lds, 16, 0, 0);
}

// ------- K0: weights fp32 [in][out] -> bf16 transposed, LN gain folded in ----
__global__ __launch_bounds__(256) void k_wt_all(
    const float* __restrict__ w0, const float* __restrict__ w1,
    const float* __restrict__ w2, const float* __restrict__ w3,
    const float* __restrict__ w4, const float* __restrict__ w5,
    const float* __restrict__ gin, const float* __restrict__ gout,
    u16* __restrict__ o0, u16* __restrict__ o1, u16* __restrict__ o2,
    u16* __restrict__ o3, u16* __restrict__ o4, u16* __restrict__ o5) {
    int sel = blockIdx.x >> 6;
    int idx = (blockIdx.x & 63) * 256 + threadIdx.x;
    const float* w = sel == 0 ? w0 : sel == 1 ? w1 : sel == 2 ? w2
                   : sel == 3 ? w3 : sel == 4 ? w4 : w5;
    u16* o = sel == 0 ? o0 : sel == 1 ? o1 : sel == 2 ? o2
           : sel == 3 ? o3 : sel == 4 ? o4 : o5;
    const float* g = (sel == 5) ? gout : gin;
    int co = idx >> 7, k = idx & 127;
    o[idx] = f2bf(g[k] * w[k * C + co]);
}

// ------- K0b: adjusted biases  b'[c] = b[c] + sum_k b_ln[k]*W[k][c] ----------
__global__ __launch_bounds__(256) void k_bias(
    const float* __restrict__ w0, const float* __restrict__ w1,
    const float* __restrict__ w2, const float* __restrict__ w3,
    const float* __restrict__ w4, const float* __restrict__ w5,
    const float* __restrict__ b0, const float* __restrict__ b1,
    const float* __restrict__ b2, const float* __restrict__ b3,
    const float* __restrict__ b4, const float* __restrict__ b5,
    const float* __restrict__ vin, const float* __restrict__ vout,
    float* __restrict__ obias) {
    int id = blockIdx.x * 256 + threadIdx.x;   // 0..767
    int m = id >> 7, cc = id & 127;
    const float* w = m == 0 ? w0 : m == 1 ? w1 : m == 2 ? w2
                   : m == 3 ? w3 : m == 4 ? w4 : w5;
    const float* b = m == 0 ? b0 : m == 1 ? b1 : m == 2 ? b2
                   : m == 3 ? b3 : m == 4 ? b4 : b5;
    const float* v = (m == 5) ? vout : vin;
    float acc = 0.f;
#pragma unroll 4
    for (int k = 0; k < 128; ++k) acc += v[k] * w[k * C + cc];
    obias[id] = b[cc] + acc;
}

// ------- fused: LN(z) + a/b/gate projections (R2 form, measured 215us) -------
__global__ __launch_bounds__(256) void k_proj_fused(
    const float* __restrict__ z, const float* __restrict__ mask,
    const u16* __restrict__ wag, const u16* __restrict__ wap,
    const u16* __restrict__ wbg, const u16* __restrict__ wbp,
    const u16* __restrict__ wgg, const float* __restrict__ biasAll,
    u16* __restrict__ aT, u16* __restrict__ bT, u16* __restrict__ gate) {
    __shared__ u16 sA[64 * PK];        // 17408 B
    __shared__ u16 sT[4][16 * ST];     //  9216 B, per-wave private 16ch x 64row
    long r0 = (long)blockIdx.x * 64;
    int tid = threadIdx.x, wave = tid >> 6, lane = tid & 63;
    int lo = lane & 15, quad = lane >> 4;

    // --- LN(z) -> sA (plain normalized, affine folded into weights/biases) ---
    {
        int rl = lane >> 2, cb = lane & 3;
        int row = wave * 16 + rl;
        const float* zr = z + (r0 + row) * C + cb * 32;
        float4 v[8];
        float s = 0.f, s2 = 0.f;
#pragma unroll
        for (int i = 0; i < 8; ++i) {
            v[i] = *(const float4*)(zr + i * 4);
            s  += v[i].x + v[i].y + v[i].z + v[i].w;
            s2 += v[i].x * v[i].x + v[i].y * v[i].y + v[i].z * v[i].z + v[i].w * v[i].w;
        }
        s += __shfl_xor(s, 1); s2 += __shfl_xor(s2, 1);
        s += __shfl_xor(s, 2); s2 += __shfl_xor(s2, 2);
        float mean = s * (1.f / 128.f);
        float rs = rsqrtf(s2 * (1.f / 128.f) - mean * mean + 1e-5f);
        u16* dst = &sA[row * PK + cb * 32];
#pragma unroll
        for (int j = 0; j < 4; ++j) {
            uint4 pk;
            pk.x = (u32)f2bf((v[2*j].x   - mean) * rs) | ((u32)f2bf((v[2*j].y   - mean) * rs) << 16);
            pk.y = (u32)f2bf((v[2*j].z   - mean) * rs) | ((u32)f2bf((v[2*j].w   - mean) * rs) << 16);
            pk.z = (u32)f2bf((v[2*j+1].x - mean) * rs) | ((u32)f2bf((v[2*j+1].y - mean) * rs) << 16);
            pk.w = (u32)f2bf((v[2*j+1].z - mean) * rs) | ((u32)f2bf((v[2*j+1].w - mean) * rs) << 16);
            *(uint4*)(dst + 8 * j) = pk;
        }
    }
    __syncthreads();

    int c0 = wave * 32;
    float msk[4][4];
#pragma unroll
    for (int mi = 0; mi < 4; ++mi)
#pragma unroll
        for (int r = 0; r < 4; ++r)
            msk[mi][r] = mask[r0 + mi * 16 + quad * 4 + r];

    u16* sTw = &sT[wave][0];

    // --- gated pair: outT[c][r] = mask*sigmoid(zn@wG+bG')*(zn@wP+bP') --------
    auto pair_stage = [&](const u16* __restrict__ wG, const float* __restrict__ bG,
                          const u16* __restrict__ wP, const float* __restrict__ bP,
                          u16* __restrict__ outT) {
#pragma unroll
        for (int nt = 0; nt < 2; ++nt) {
            int c = c0 + nt * 16 + lo;
            bf16x8 fG[4], fP[4];
#pragma unroll
            for (int ki = 0; ki < 4; ++ki) {
                fG[ki] = *(const bf16x8*)(wG + c * C + ki * 32 + quad * 8);
                fP[ki] = *(const bf16x8*)(wP + c * C + ki * 32 + quad * 8);
            }
            f32x4 aG[4], aP[4];
#pragma unroll
            for (int mi = 0; mi < 4; ++mi) { aG[mi] = (f32x4)(0.f); aP[mi] = (f32x4)(0.f); }
#pragma unroll
            for (int mi = 0; mi < 4; ++mi)
#pragma unroll
                for (int ki = 0; ki < 4; ++ki) {
                    bf16x8 av = *(const bf16x8*)(&sA[(mi * 16 + lo) * PK + ki * 32 + quad * 8]);
                    aG[mi] = __builtin_amdgcn_mfma_f32_16x16x32_bf16(av, fG[ki], aG[mi], 0, 0, 0);
                    aP[mi] = __builtin_amdgcn_mfma_f32_16x16x32_bf16(av, fP[ki], aP[mi], 0, 0, 0);
                }
            float bGv = bG[c], bPv = bP[c];
#pragma unroll
            for (int mi = 0; mi < 4; ++mi) {
                float v0 = msk[mi][0] * sigmoidf(aG[mi][0] + bGv) * (aP[mi][0] + bPv);
                float v1 = msk[mi][1] * sigmoidf(aG[mi][1] + bGv) * (aP[mi][1] + bPv);
                float v2 = msk[mi][2] * sigmoidf(aG[mi][2] + bGv) * (aP[mi][2] + bPv);
                float v3 = msk[mi][3] * sigmoidf(aG[mi][3] + bGv) * (aP[mi][3] + bPv);
                uint2 pk;
                pk.x = (u32)f2bf(v0) | ((u32)f2bf(v1) << 16);
                pk.y = (u32)f2bf(v2) | ((u32)f2bf(v3) << 16);
                *(uint2*)(&sTw[lo * ST + mi * 16 + quad * 4]) = pk;
            }
            // per-wave copy out: 16 ch x 64 rows, no barrier needed (wave-private)
            {
                int cl = lane >> 2, pr = lane & 3;
                uint4 x0 = *(const uint4*)(&sTw[cl * ST + pr * 16]);
                uint4 x1 = *(const uint4*)(&sTw[cl * ST + pr * 16 + 8]);
                u16* g = outT + (long)(c0 + nt * 16 + cl) * NN + r0 + pr * 16;
                *(uint4*)(g) = x0;
                *(uint4*)(g + 8) = x1;
            }
        }
    };
    pair_stage(wag, biasAll + 0,   wap, biasAll + 128, aT);
    pair_stage(wbg, biasAll + 256, wbp, biasAll + 384, bT);

    // --- gate: gate[r][c] = sigmoid(zn@w_g + b_g') ---------------------------
    {
        f32x4 gA[2][4];
#pragma unroll
        for (int nt = 0; nt < 2; ++nt) {
            bf16x8 gF[4];
#pragma unroll
            for (int ki = 0; ki < 4; ++ki)
                gF[ki] = *(const bf16x8*)(wgg + (c0 + nt * 16 + lo) * C + ki * 32 + quad * 8);
#pragma unroll
            for (int mi = 0; mi < 4; ++mi) gA[nt][mi] = (f32x4)(0.f);
#pragma unroll
            for (int mi = 0; mi < 4; ++mi)
#pragma unroll
                for (int ki = 0; ki < 4; ++ki) {
                    bf16x8 av = *(const bf16x8*)(&sA[(mi * 16 + lo) * PK + ki * 32 + quad * 8]);
                    gA[nt][mi] = __builtin_amdgcn_mfma_f32_16x16x32_bf16(av, gF[ki], gA[nt][mi], 0, 0, 0);
                }
        }
        __syncthreads();   // all waves done reading sA before overwrite
        const float* bg5 = biasAll + 512;
#pragma unroll
        for (int nt = 0; nt < 2; ++nt) {
            int c = c0 + nt * 16 + lo;
            float bv = bg5[c];
#pragma unroll
            for (int mi = 0; mi < 4; ++mi)
#pragma unroll
                for (int r = 0; r < 4; ++r)
                    sA[(mi * 16 + quad * 4 + r) * PK + c] = f2bf(sigmoidf(gA[nt][mi][r] + bv));
        }
        __syncthreads();
#pragma unroll
        for (int p = 0; p < 4; ++p) {
            int linear = p * 2048 + tid * 8;
            int row = linear >> 7, k = linear & 127;
            *(uint4*)(gate + (r0 + row) * C + k) = *(const uint4*)(&sA[row * PK + k]);
        }
    }
}

// ------- K3: per-channel 512x512x512 BT-GEMM, global_load_lds staging --------
// x_t[c][i][j] = sum_k a_t[c][i][k] * b_t[c][j][k]
// Linear LDS [128][32] u16 (64B rows): gload_lds chunk = 1024B = 16 rows;
// fragment-read bank window = (row&1)*16 + quad*4 -> 8 lanes/window (balanced).
__global__ __launch_bounds__(256) void k_tri(const u16* __restrict__ aT,
                                             const u16* __restrict__ bT,
                                             u16* __restrict__ xT) {
    __shared__ u16 sA[128 * 32];   // 8 KB
    __shared__ u16 sB[128 * 32];   // 8 KB
    int c = blockIdx.y;
    int i0 = (blockIdx.x >> 2) * 128, j0 = (blockIdx.x & 3) * 128;
    const u16* aBase = aT + (long)c * NN + (long)i0 * N;
    const u16* bBase = bT + (long)c * NN + (long)j0 * N;
    int tid = threadIdx.x;
    int wave = tid >> 6, lane = tid & 63, lo = lane & 15, quad = lane >> 4;
    int mq = (wave >> 1) * 64, nq = (wave & 1) * 64;
    int ld_row = lane >> 2;            // 0..15 within a 16-row chunk
    int ld_col = (lane & 3) * 8;       // u16 col, 16B per lane
    f32x4 acc[4][4];
#pragma unroll
    for (int mi = 0; mi < 4; ++mi)
#pragma unroll
        for (int ni = 0; ni < 4; ++ni) acc[mi][ni] = (f32x4)(0.f);
    for (int kk = 0; kk < N; kk += 32) {
        __syncthreads();               // prev MFMA phase done reading LDS
#pragma unroll
        for (int h = 0; h < 2; ++h) {
            int ch = wave + h * 4;     // chunk 0..7 (16 rows each)
            int r = ch * 16 + ld_row;  // tile row 0..127
            gload16(aBase + (long)r * N + kk + ld_col, &sA[ch * 512]);
            gload16(bBase + (long)r * N + kk + ld_col, &sB[ch * 512]);
        }
        __syncthreads();               // vmcnt drain -> LDS data ready
        bf16x8 af[4], bfr[4];
#pragma unroll
        for (int mi = 0; mi < 4; ++mi)
            af[mi] = *(const bf16x8*)(&sA[(mq + mi * 16 + lo) * 32 + quad * 8]);
#pragma unroll
        for (int ni = 0; ni < 4; ++ni)
            bfr[ni] = *(const bf16x8*)(&sB[(nq + ni * 16 + lo) * 32 + quad * 8]);
#pragma unroll
        for (int mi = 0; mi < 4; ++mi)
#pragma unroll
            for (int ni = 0; ni < 4; ++ni)
                acc[mi][ni] = __builtin_amdgcn_mfma_f32_16x16x32_bf16(af[mi], bfr[ni], acc[mi][ni], 0, 0, 0);
    }
    u16* outBase = xT + (long)c * NN;
#pragma unroll
    for (int mi = 0; mi < 4; ++mi)
#pragma unroll
        for (int ni = 0; ni < 4; ++ni)
#pragma unroll
            for (int r = 0; r < 4; ++r) {
                int gi = i0 + mq + mi * 16 + quad * 4 + r;
                int gj = j0 + nq + ni * 16 + lo;
                outBase[(long)gi * N + gj] = f2bf(acc[mi][ni][r]);
            }
}

// ------- K4: LN(x) @ w_z' + b_z', * gate -> out fp32 (ln_out folded) ---------
__global__ __launch_bounds__(256) void k_out(
    const u16* __restrict__ xT, const u16* __restrict__ gate,
    const u16* __restrict__ wzT, const float* __restrict__ bz,
    float* __restrict__ out) {
    __shared__ float sX[64 * PX];
    __shared__ u16 sA[64 * PK];
    __shared__ float sRed[2][4][64];
    __shared__ float2 sMV[64];
    long r0 = (long)blockIdx.x * 64;
    int tid = threadIdx.x;
#pragma unroll
    for (int p = 0; p < 4; ++p) {
        int linear = p * 2048 + tid * 8;
        int cc = linear >> 6, jr = linear & 63;
        uint4 v = *(const uint4*)(xT + (long)cc * NN + r0 + jr);
        u16* u = (u16*)&v;
#pragma unroll
        for (int e = 0; e < 8; ++e) sX[(jr + e) * PX + cc] = bf2f(u[e]);
    }
    __syncthreads();
    {
        int jr = tid & 63, part = tid >> 6;
        float s = 0, s2 = 0;
#pragma unroll
        for (int c = part * 32; c < part * 32 + 32; ++c) {
            float v = sX[jr * PX + c];
            s += v; s2 += v * v;
        }
        sRed[0][part][jr] = s; sRed[1][part][jr] = s2;
    }
    __syncthreads();
    if (tid < 64) {
        float S = 0, S2 = 0;
#pragma unroll
        for (int p = 0; p < 4; ++p) { S += sRed[0][p][tid]; S2 += sRed[1][p][tid]; }
        float mean = S * (1.f / 128.f);
        float var = S2 * (1.f / 128.f) - mean * mean;
        sMV[tid] = make_float2(mean, rsqrtf(var + 1e-5f));
    }
    __syncthreads();
    {
        int row = tid & 63, c0 = (tid >> 6) * 32;
        float2 mv = sMV[row];
#pragma unroll
        for (int c = c0; c < c0 + 32; ++c)
            sA[row * PK + c] = f2bf((sX[row * PX + c] - mv.x) * mv.y);
    }
    __syncthreads();
    int wave = tid >> 6, lane = tid & 63, lo = lane & 15, quad = lane >> 4;
    int msub = wave * 16;
    bf16x8 av[4];
#pragma unroll
    for (int ki = 0; ki < 4; ++ki)
        av[ki] = *(const bf16x8*)(&sA[(msub + lo) * PK + ki * 32 + quad * 8]);
    f32x4 acc[8];
#pragma unroll
    for (int nt = 0; nt < 8; ++nt) acc[nt] = (f32x4)(0.f);
#pragma unroll
    for (int nt = 0; nt < 8; ++nt)
#pragma unroll
        for (int ki = 0; ki < 4; ++ki) {
            bf16x8 b8 = *(const bf16x8*)(wzT + (nt * 16 + lo) * C + ki * 32 + quad * 8);
            acc[nt] = __builtin_amdgcn_mfma_f32_16x16x32_bf16(av[ki], b8, acc[nt], 0, 0, 0);
        }
#pragma unroll
    for (int nt = 0; nt < 8; ++nt) {
        int c = nt * 16 + lo;
        float bzv = bz[c];
#pragma unroll
        for (int r = 0; r < 4; ++r) {
            int row = msub + quad * 4 + r;
            long rr = r0 + row;
            float g = bf2f(gate[rr * C + c]);
            out[rr * C + c] = (acc[nt][r] + bzv) * g;
        }
    }
}

extern "C" void kernel_launch(void* const* d_in, const int* in_sizes, int n_in,
                              void* d_out, int out_size, void* d_ws, size_t ws_size,
                              hipStream_t stream) {
    const float* z       = (const float*)d_in[0];
    const float* mask    = (const float*)d_in[1];
    const float* w_ag    = (const float*)d_in[2];
    const float* b_ag    = (const float*)d_in[3];
    const float* w_ap    = (const float*)d_in[4];
    const float* b_ap    = (const float*)d_in[5];
    const float* w_bg    = (const float*)d_in[6];
    const float* b_bg    = (const float*)d_in[7];
    const float* w_bp    = (const float*)d_in[8];
    const float* b_bp    = (const float*)d_in[9];
    const float* w_g     = (const float*)d_in[10];
    const float* b_g     = (const float*)d_in[11];
    const float* w_z     = (const float*)d_in[12];
    const float* b_z     = (const float*)d_in[13];
    const float* ln_in_g = (const float*)d_in[14];
    const float* ln_in_b = (const float*)d_in[15];
    const float* ln_out_g= (const float*)d_in[16];
    const float* ln_out_b= (const float*)d_in[17];
    float* out = (float*)d_out;

    char* ws = (char*)d_ws;
    u16* a_t  = (u16*)(ws);                          // 64 MB
    u16* b_t  = (u16*)(ws + 67108864L);              // 64 MB
    u16* gate = (u16*)(ws + 134217728L);             // 64 MB
    u16* x_t  = (u16*)(ws + 201326592L);             // 64 MB
    u16* wag_t = (u16*)(ws + 268435456L);
    u16* wap_t = wag_t + 16384;
    u16* wbg_t = wag_t + 32768;
    u16* wbp_t = wag_t + 49152;
    u16* wg_t  = wag_t + 65536;
    u16* wz_t  = wag_t + 81920;
    float* biasAdj = (float*)(ws + 268435456L + 196608L);   // 6*128 fp32

    k_wt_all<<<384, 256, 0, stream>>>(w_ag, w_ap, w_bg, w_bp, w_g, w_z,
                                      ln_in_g, ln_out_g,
                                      wag_t, wap_t, wbg_t, wbp_t, wg_t, wz_t);

    k_bias<<<3, 256, 0, stream>>>(w_ag, w_ap, w_bg, w_bp, w_g, w_z,
                                  b_ag, b_ap, b_bg, b_bp, b_g, b_z,
                                  ln_in_b, ln_out_b, biasAdj);

    k_proj_fused<<<NN / 64, 256, 0, stream>>>(
        z, mask, wag_t, wap_t, wbg_t, wbp_t, wg_t, biasAdj,
        a_t, b_t, gate);

    k_tri<<<dim3(16, 128), 256, 0, stream>>>(a_t, b_t, x_t);

    k_out<<<NN / 64, 256, 0, stream>>>(x_t, gate, wz_t, biasAdj + 640, out);
}

// Round 4
// 558.382 us; speedup vs baseline: 1.5158x; 1.0375x over previous
//
#include <hip/hip_runtime.h>
#include <hip/hip_bf16.h>
#include <math.h>

// TriangleMultiplicativeUpdate (outgoing), B=1 N=512 C_Z=C_H=128, fp32 in/out.
// R5: k_proj_fused single-pass restructure.
//   The R2/R4 form traversed sA three times (pairA -> pairB -> gate), each a
//   serial {weight-load -> 32 ds_read + <=2 MFMA each -> VALU epilogue} chain;
//   counters showed no pipe >35% busy (latency-bound). Now ONE traversal:
//   per (mi,ki) a single ds_read_b128 feeds 5 MFMAs (aG,aP,bG,bP,gate),
//   all 20 weight frags load up-front (MLP), epilogues A/B use separate
//   per-wave sT halves. ds_read count 96->32 per wave. VGPR ~210 -> (256,2);
//   occupancy proven non-binding (R1 21% vs R2 11%: same 215us).
//   k_tri keeps R4 gload_lds form (neutral, frees VGPR); k_out/k_wt/k_bias
//   unchanged.

#define N 512
#define C 128
#define NN (N*N)
#define PK 136   // padded LDS stride (u16) for MFMA A tiles
#define PX 137   // padded LDS stride for fp32 x-tile transpose (k_out)
#define ST 72    // per-channel stride (u16) in per-wave transpose buffer

typedef __attribute__((ext_vector_type(8))) short bf16x8;
typedef __attribute__((ext_vector_type(4))) float f32x4;
typedef unsigned short u16;
typedef unsigned int u32;

__device__ __forceinline__ u16 f2bf(float f) {
    u32 u = __builtin_bit_cast(u32, f);
    u = (u + 0x7fffu + ((u >> 16) & 1u)) >> 16;
    return (u16)u;
}
__device__ __forceinline__ float bf2f(u16 h) {
    return __builtin_bit_cast(float, ((u32)h) << 16);
}
__device__ __forceinline__ float sigmoidf(float x) {
    return 1.f / (1.f + __expf(-x));
}
// async global->LDS, 16B per lane; lds dest must be wave-uniform (HW adds lane*16)
__device__ __forceinline__ void gload16(const u16* g, u16* lds) {
    __builtin_amdgcn_global_load_lds(
        (const __attribute__((address_space(1))) unsigned int*)g,
        (__attribute__((address_space(3))) unsigned int*)lds, 16, 0, 0);
}

// ------- K0: weights fp32 [in][out] -> bf16 transposed, LN gain folded in ----
__global__ __launch_bounds__(256) void k_wt_all(
    const float* __restrict__ w0, const float* __restrict__ w1,
    const float* __restrict__ w2, const float* __restrict__ w3,
    const float* __restrict__ w4, const float* __restrict__ w5,
    const float* __restrict__ gin, const float* __restrict__ gout,
    u16* __restrict__ o0, u16* __restrict__ o1, u16* __restrict__ o2,
    u16* __restrict__ o3, u16* __restrict__ o4, u16* __restrict__ o5) {
    int sel = blockIdx.x >> 6;
    int idx = (blockIdx.x & 63) * 256 + threadIdx.x;
    const float* w = sel == 0 ? w0 : sel == 1 ? w1 : sel == 2 ? w2
                   : sel == 3 ? w3 : sel == 4 ? w4 : w5;
    u16* o = sel == 0 ? o0 : sel == 1 ? o1 : sel == 2 ? o2
           : sel == 3 ? o3 : sel == 4 ? o4 : o5;
    const float* g = (sel == 5) ? gout : gin;
    int co = idx >> 7, k = idx & 127;
    o[idx] = f2bf(g[k] * w[k * C + co]);
}

// ------- K0b: adjusted biases  b'[c] = b[c] + sum_k b_ln[k]*W[k][c] ----------
__global__ __launch_bounds__(256) void k_bias(
    const float* __restrict__ w0, const float* __restrict__ w1,
    const float* __restrict__ w2, const float* __restrict__ w3,
    const float* __restrict__ w4, const float* __restrict__ w5,
    const float* __restrict__ b0, const float* __restrict__ b1,
    const float* __restrict__ b2, const float* __restrict__ b3,
    const float* __restrict__ b4, const float* __restrict__ b5,
    const float* __restrict__ vin, const float* __restrict__ vout,
    float* __restrict__ obias) {
    int id = blockIdx.x * 256 + threadIdx.x;   // 0..767
    int m = id >> 7, cc = id & 127;
    const float* w = m == 0 ? w0 : m == 1 ? w1 : m == 2 ? w2
                   : m == 3 ? w3 : m == 4 ? w4 : w5;
    const float* b = m == 0 ? b0 : m == 1 ? b1 : m == 2 ? b2
                   : m == 3 ? b3 : m == 4 ? b4 : b5;
    const float* v = (m == 5) ? vout : vin;
    float acc = 0.f;
#pragma unroll 4
    for (int k = 0; k < 128; ++k) acc += v[k] * w[k * C + cc];
    obias[id] = b[cc] + acc;
}

// ------- fused: LN(z) + 5 projections in ONE sA traversal --------------------
// block = 256 threads, 64 rows. Wave w owns output cols [w*32, w*32+32).
__global__ __launch_bounds__(256, 2) void k_proj_fused(
    const float* __restrict__ z, const float* __restrict__ mask,
    const u16* __restrict__ wag, const u16* __restrict__ wap,
    const u16* __restrict__ wbg, const u16* __restrict__ wbp,
    const u16* __restrict__ wgg, const float* __restrict__ biasAll,
    u16* __restrict__ aT, u16* __restrict__ bT, u16* __restrict__ gate) {
    __shared__ u16 sA[64 * PK];           // 17408 B
    __shared__ u16 sT[4][2][16 * ST];     // 18432 B, per-wave x {A,B} halves
    long r0 = (long)blockIdx.x * 64;
    int tid = threadIdx.x, wave = tid >> 6, lane = tid & 63;
    int lo = lane & 15, quad = lane >> 4;

    // --- LN(z) -> sA (plain normalized, affine folded into weights/biases) ---
    {
        int rl = lane >> 2, cb = lane & 3;
        int row = wave * 16 + rl;
        const float* zr = z + (r0 + row) * C + cb * 32;
        float4 v[8];
        float s = 0.f, s2 = 0.f;
#pragma unroll
        for (int i = 0; i < 8; ++i) {
            v[i] = *(const float4*)(zr + i * 4);
            s  += v[i].x + v[i].y + v[i].z + v[i].w;
            s2 += v[i].x * v[i].x + v[i].y * v[i].y + v[i].z * v[i].z + v[i].w * v[i].w;
        }
        s += __shfl_xor(s, 1); s2 += __shfl_xor(s2, 1);
        s += __shfl_xor(s, 2); s2 += __shfl_xor(s2, 2);
        float mean = s * (1.f / 128.f);
        float rs = rsqrtf(s2 * (1.f / 128.f) - mean * mean + 1e-5f);
        u16* dst = &sA[row * PK + cb * 32];
#pragma unroll
        for (int j = 0; j < 4; ++j) {
            uint4 pk;
            pk.x = (u32)f2bf((v[2*j].x   - mean) * rs) | ((u32)f2bf((v[2*j].y   - mean) * rs) << 16);
            pk.y = (u32)f2bf((v[2*j].z   - mean) * rs) | ((u32)f2bf((v[2*j].w   - mean) * rs) << 16);
            pk.z = (u32)f2bf((v[2*j+1].x - mean) * rs) | ((u32)f2bf((v[2*j+1].y - mean) * rs) << 16);
            pk.w = (u32)f2bf((v[2*j+1].z - mean) * rs) | ((u32)f2bf((v[2*j+1].w - mean) * rs) << 16);
            *(uint4*)(dst + 8 * j) = pk;
        }
    }
    __syncthreads();

    int c0 = wave * 32;
    float msk[4][4];
#pragma unroll
    for (int mi = 0; mi < 4; ++mi)
#pragma unroll
        for (int r = 0; r < 4; ++r)
            msk[mi][r] = mask[r0 + mi * 16 + quad * 4 + r];

    // gated epilogue: pack masked sigmoid(G)*P into wave-private sT half,
    // then per-wave coalesced copy-out (no barrier; wave-private buffer).
    auto epi = [&](const f32x4* G, const f32x4* P, float bGv, float bPv,
                   u16* sTh, u16* __restrict__ outT, int cch) {
#pragma unroll
        for (int mi = 0; mi < 4; ++mi) {
            float v0 = msk[mi][0] * sigmoidf(G[mi][0] + bGv) * (P[mi][0] + bPv);
            float v1 = msk[mi][1] * sigmoidf(G[mi][1] + bGv) * (P[mi][1] + bPv);
            float v2 = msk[mi][2] * sigmoidf(G[mi][2] + bGv) * (P[mi][2] + bPv);
            float v3 = msk[mi][3] * sigmoidf(G[mi][3] + bGv) * (P[mi][3] + bPv);
            uint2 pk;
            pk.x = (u32)f2bf(v0) | ((u32)f2bf(v1) << 16);
            pk.y = (u32)f2bf(v2) | ((u32)f2bf(v3) << 16);
            *(uint2*)(&sTh[lo * ST + mi * 16 + quad * 4]) = pk;
        }
        int cl = lane >> 2, pr = lane & 3;
        uint4 x0 = *(const uint4*)(&sTh[cl * ST + pr * 16]);
        uint4 x1 = *(const uint4*)(&sTh[cl * ST + pr * 16 + 8]);
        u16* g = outT + (long)(cch + cl) * NN + r0 + pr * 16;
        *(uint4*)(g) = x0;
        *(uint4*)(g + 8) = x1;
    };

    f32x4 gG[2][4];
#pragma unroll
    for (int nt = 0; nt < 2; ++nt)
#pragma unroll
        for (int mi = 0; mi < 4; ++mi) gG[nt][mi] = (f32x4)(0.f);

#pragma unroll
    for (int nt = 0; nt < 2; ++nt) {
        int c = c0 + nt * 16 + lo;
        // all 20 weight fragments issue together (max memory-level parallelism)
        bf16x8 fAG[4], fAP[4], fBG[4], fBP[4], fGG[4];
#pragma unroll
        for (int ki = 0; ki < 4; ++ki) {
            fAG[ki] = *(const bf16x8*)(wag + c * C + ki * 32 + quad * 8);
            fAP[ki] = *(const bf16x8*)(wap + c * C + ki * 32 + quad * 8);
            fBG[ki] = *(const bf16x8*)(wbg + c * C + ki * 32 + quad * 8);
            fBP[ki] = *(const bf16x8*)(wbp + c * C + ki * 32 + quad * 8);
            fGG[ki] = *(const bf16x8*)(wgg + c * C + ki * 32 + quad * 8);
        }
        f32x4 aG[4], aP[4], bG[4], bP[4];
#pragma unroll
        for (int mi = 0; mi < 4; ++mi) {
            aG[mi] = (f32x4)(0.f); aP[mi] = (f32x4)(0.f);
            bG[mi] = (f32x4)(0.f); bP[mi] = (f32x4)(0.f);
        }
        // ONE sA traversal: each ds_read_b128 feeds 5 MFMAs
#pragma unroll
        for (int mi = 0; mi < 4; ++mi)
#pragma unroll
            for (int ki = 0; ki < 4; ++ki) {
                bf16x8 av = *(const bf16x8*)(&sA[(mi * 16 + lo) * PK + ki * 32 + quad * 8]);
                aG[mi]     = __builtin_amdgcn_mfma_f32_16x16x32_bf16(av, fAG[ki], aG[mi], 0, 0, 0);
                aP[mi]     = __builtin_amdgcn_mfma_f32_16x16x32_bf16(av, fAP[ki], aP[mi], 0, 0, 0);
                bG[mi]     = __builtin_amdgcn_mfma_f32_16x16x32_bf16(av, fBG[ki], bG[mi], 0, 0, 0);
                bP[mi]     = __builtin_amdgcn_mfma_f32_16x16x32_bf16(av, fBP[ki], bP[mi], 0, 0, 0);
                gG[nt][mi] = __builtin_amdgcn_mfma_f32_16x16x32_bf16(av, fGG[ki], gG[nt][mi], 0, 0, 0);
            }
        epi(aG, aP, biasAll[c],       biasAll[128 + c], &sT[wave][0][0], aT, c0 + nt * 16);
        epi(bG, bP, biasAll[256 + c], biasAll[384 + c], &sT[wave][1][0], bT, c0 + nt * 16);
    }

    // --- gate epilogue: sigmoid(gG)+bias -> sA staging -> coalesced store ----
    __syncthreads();   // all waves done reading sA before overwrite
    const float* bg5 = biasAll + 512;
#pragma unroll
    for (int nt = 0; nt < 2; ++nt) {
        int c = c0 + nt * 16 + lo;
        float bv = bg5[c];
#pragma unroll
        for (int mi = 0; mi < 4; ++mi)
#pragma unroll
            for (int r = 0; r < 4; ++r)
                sA[(mi * 16 + quad * 4 + r) * PK + c] = f2bf(sigmoidf(gG[nt][mi][r] + bv));
    }
    __syncthreads();
#pragma unroll
    for (int p = 0; p < 4; ++p) {
        int linear = p * 2048 + tid * 8;
        int row = linear >> 7, k = linear & 127;
        *(uint4*)(gate + (r0 + row) * C + k) = *(const uint4*)(&sA[row * PK + k]);
    }
}

// ------- K3: per-channel 512x512x512 BT-GEMM, global_load_lds staging --------
// x_t[c][i][j] = sum_k a_t[c][i][k] * b_t[c][j][k]
__global__ __launch_bounds__(256) void k_tri(const u16* __restrict__ aT,
                                             const u16* __restrict__ bT,
                                             u16* __restrict__ xT) {
    __shared__ u16 sA[128 * 32];   // 8 KB
    __shared__ u16 sB[128 * 32];   // 8 KB
    int c = blockIdx.y;
    int i0 = (blockIdx.x >> 2) * 128, j0 = (blockIdx.x & 3) * 128;
    const u16* aBase = aT + (long)c * NN + (long)i0 * N;
    const u16* bBase = bT + (long)c * NN + (long)j0 * N;
    int tid = threadIdx.x;
    int wave = tid >> 6, lane = tid & 63, lo = lane & 15, quad = lane >> 4;
    int mq = (wave >> 1) * 64, nq = (wave & 1) * 64;
    int ld_row = lane >> 2;            // 0..15 within a 16-row chunk
    int ld_col = (lane & 3) * 8;       // u16 col, 16B per lane
    f32x4 acc[4][4];
#pragma unroll
    for (int mi = 0; mi < 4; ++mi)
#pragma unroll
        for (int ni = 0; ni < 4; ++ni) acc[mi][ni] = (f32x4)(0.f);
    for (int kk = 0; kk < N; kk += 32) {
        __syncthreads();               // prev MFMA phase done reading LDS
#pragma unroll
        for (int h = 0; h < 2; ++h) {
            int ch = wave + h * 4;     // chunk 0..7 (16 rows each)
            int r = ch * 16 + ld_row;  // tile row 0..127
            gload16(aBase + (long)r * N + kk + ld_col, &sA[ch * 512]);
            gload16(bBase + (long)r * N + kk + ld_col, &sB[ch * 512]);
        }
        __syncthreads();               // vmcnt drain -> LDS data ready
        bf16x8 af[4], bfr[4];
#pragma unroll
        for (int mi = 0; mi < 4; ++mi)
            af[mi] = *(const bf16x8*)(&sA[(mq + mi * 16 + lo) * 32 + quad * 8]);
#pragma unroll
        for (int ni = 0; ni < 4; ++ni)
            bfr[ni] = *(const bf16x8*)(&sB[(nq + ni * 16 + lo) * 32 + quad * 8]);
#pragma unroll
        for (int mi = 0; mi < 4; ++mi)
#pragma unroll
            for (int ni = 0; ni < 4; ++ni)
                acc[mi][ni] = __builtin_amdgcn_mfma_f32_16x16x32_bf16(af[mi], bfr[ni], acc[mi][ni], 0, 0, 0);
    }
    u16* outBase = xT + (long)c * NN;
#pragma unroll
    for (int mi = 0; mi < 4; ++mi)
#pragma unroll
        for (int ni = 0; ni < 4; ++ni)
#pragma unroll
            for (int r = 0; r < 4; ++r) {
                int gi = i0 + mq + mi * 16 + quad * 4 + r;
                int gj = j0 + nq + ni * 16 + lo;
                outBase[(long)gi * N + gj] = f2bf(acc[mi][ni][r]);
            }
}

// ------- K4: LN(x) @ w_z' + b_z', * gate -> out fp32 (ln_out folded) ---------
__global__ __launch_bounds__(256) void k_out(
    const u16* __restrict__ xT, const u16* __restrict__ gate,
    const u16* __restrict__ wzT, const float* __restrict__ bz,
    float* __restrict__ out) {
    __shared__ float sX[64 * PX];
    __shared__ u16 sA[64 * PK];
    __shared__ float sRed[2][4][64];
    __shared__ float2 sMV[64];
    long r0 = (long)blockIdx.x * 64;
    int tid = threadIdx.x;
#pragma unroll
    for (int p = 0; p < 4; ++p) {
        int linear = p * 2048 + tid * 8;
        int cc = linear >> 6, jr = linear & 63;
        uint4 v = *(const uint4*)(xT + (long)cc * NN + r0 + jr);
        u16* u = (u16*)&v;
#pragma unroll
        for (int e = 0; e < 8; ++e) sX[(jr + e) * PX + cc] = bf2f(u[e]);
    }
    __syncthreads();
    {
        int jr = tid & 63, part = tid >> 6;
        float s = 0, s2 = 0;
#pragma unroll
        for (int c = part * 32; c < part * 32 + 32; ++c) {
            float v = sX[jr * PX + c];
            s += v; s2 += v * v;
        }
        sRed[0][part][jr] = s; sRed[1][part][jr] = s2;
    }
    __syncthreads();
    if (tid < 64) {
        float S = 0, S2 = 0;
#pragma unroll
        for (int p = 0; p < 4; ++p) { S += sRed[0][p][tid]; S2 += sRed[1][p][tid]; }
        float mean = S * (1.f / 128.f);
        float var = S2 * (1.f / 128.f) - mean * mean;
        sMV[tid] = make_float2(mean, rsqrtf(var + 1e-5f));
    }
    __syncthreads();
    {
        int row = tid & 63, c0 = (tid >> 6) * 32;
        float2 mv = sMV[row];
#pragma unroll
        for (int c = c0; c < c0 + 32; ++c)
            sA[row * PK + c] = f2bf((sX[row * PX + c] - mv.x) * mv.y);
    }
    __syncthreads();
    int wave = tid >> 6, lane = tid & 63, lo = lane & 15, quad = lane >> 4;
    int msub = wave * 16;
    bf16x8 av[4];
#pragma unroll
    for (int ki = 0; ki < 4; ++ki)
        av[ki] = *(const bf16x8*)(&sA[(msub + lo) * PK + ki * 32 + quad * 8]);
    f32x4 acc[8];
#pragma unroll
    for (int nt = 0; nt < 8; ++nt) acc[nt] = (f32x4)(0.f);
#pragma unroll
    for (int nt = 0; nt < 8; ++nt)
#pragma unroll
        for (int ki = 0; ki < 4; ++ki) {
            bf16x8 b8 = *(const bf16x8*)(wzT + (nt * 16 + lo) * C + ki * 32 + quad * 8);
            acc[nt] = __builtin_amdgcn_mfma_f32_16x16x32_bf16(av[ki], b8, acc[nt], 0, 0, 0);
        }
#pragma unroll
    for (int nt = 0; nt < 8; ++nt) {
        int c = nt * 16 + lo;
        float bzv = bz[c];
#pragma unroll
        for (int r = 0; r < 4; ++r) {
            int row = msub + quad * 4 + r;
            long rr = r0 + row;
            float g = bf2f(gate[rr * C + c]);
            out[rr * C + c] = (acc[nt][r] + bzv) * g;
        }
    }
}

extern "C" void kernel_launch(void* const* d_in, const int* in_sizes, int n_in,
                              void* d_out, int out_size, void* d_ws, size_t ws_size,
                              hipStream_t stream) {
    const float* z       = (const float*)d_in[0];
    const float* mask    = (const float*)d_in[1];
    const float* w_ag    = (const float*)d_in[2];
    const float* b_ag    = (const float*)d_in[3];
    const float* w_ap    = (const float*)d_in[4];
    const float* b_ap    = (const float*)d_in[5];
    const float* w_bg    = (const float*)d_in[6];
    const float* b_bg    = (const float*)d_in[7];
    const float* w_bp    = (const float*)d_in[8];
    const float* b_bp    = (const float*)d_in[9];
    const float* w_g     = (const float*)d_in[10];
    const float* b_g     = (const float*)d_in[11];
    const float* w_z     = (const float*)d_in[12];
    const float* b_z     = (const float*)d_in[13];
    const float* ln_in_g = (const float*)d_in[14];
    const float* ln_in_b = (const float*)d_in[15];
    const float* ln_out_g= (const float*)d_in[16];
    const float* ln_out_b= (const float*)d_in[17];
    float* out = (float*)d_out;

    char* ws = (char*)d_ws;
    u16* a_t  = (u16*)(ws);                          // 64 MB
    u16* b_t  = (u16*)(ws + 67108864L);              // 64 MB
    u16* gate = (u16*)(ws + 134217728L);             // 64 MB
    u16* x_t  = (u16*)(ws + 201326592L);             // 64 MB
    u16* wag_t = (u16*)(ws + 268435456L);
    u16* wap_t = wag_t + 16384;
    u16* wbg_t = wag_t + 32768;
    u16* wbp_t = wag_t + 49152;
    u16* wg_t  = wag_t + 65536;
    u16* wz_t  = wag_t + 81920;
    float* biasAdj = (float*)(ws + 268435456L + 196608L);   // 6*128 fp32

    k_wt_all<<<384, 256, 0, stream>>>(w_ag, w_ap, w_bg, w_bp, w_g, w_z,
                                      ln_in_g, ln_out_g,
                                      wag_t, wap_t, wbg_t, wbp_t, wg_t, wz_t);

    k_bias<<<3, 256, 0, stream>>>(w_ag, w_ap, w_bg, w_bp, w_g, w_z,
                                  b_ag, b_ap, b_bg, b_bp, b_g, b_z,
                                  ln_in_b, ln_out_b, biasAdj);

    k_proj_fused<<<NN / 64, 256, 0, stream>>>(
        z, mask, wag_t, wap_t, wbg_t, wbp_t, wg_t, biasAdj,
        a_t, b_t, gate);

    k_tri<<<dim3(16, 128), 256, 0, stream>>>(a_t, b_t, x_t);

    k_out<<<NN / 64, 256, 0, stream>>>(x_t, gate, wz_t, biasAdj + 640, out);
}

// Round 5
// 558.005 us; speedup vs baseline: 1.5168x; 1.0007x over previous
//
#include <hip/hip_runtime.h>
#include <hip/hip_bf16.h>
#include <math.h>

// TriangleMultiplicativeUpdate (outgoing), B=1 N=512 C_Z=C_H=128, fp32 in/out.
// R6: attack k_tri + k_out (now ~350us combined vs k_proj 191us).
//   k_tri: T3 minimum 2-phase double-buffer — stage tile t+1 BEFORE computing
//     tile t; ONE barrier per phase (implicit vmcnt drain covers loads that
//     flew during compute). Barriers 32->17, load latency hidden. LDS 32KB.
//   k_out: LN-after-GEMM identity  LN(x)@W' = rs*(x@W' - m*colsum') + bz'.
//     MFMA the RAW bf16 x; apply (m, rs) per point in epilogue. Deletes the
//     fp32 sX buffer (35KB) and the whole normalize pass: LDS 55->20KB
//     (2->~8 blocks/CU). colsum' computed from bf16-rounded W' (k_bias slot 6)
//     so the identity matches the MFMA operand exactly.
//   k_proj_fused kept as R5 (measured 191us); k_wt_all unchanged.

#define N 512
#define C 128
#define NN (N*N)
#define PK 136   // padded LDS stride (u16) for MFMA A tiles (rows 16B-aligned)
#define ST 72    // per-channel stride (u16) in per-wave transpose buffer

typedef __attribute__((ext_vector_type(8))) short bf16x8;
typedef __attribute__((ext_vector_type(4))) float f32x4;
typedef unsigned short u16;
typedef unsigned int u32;

__device__ __forceinline__ u16 f2bf(float f) {
    u32 u = __builtin_bit_cast(u32, f);
    u = (u + 0x7fffu + ((u >> 16) & 1u)) >> 16;
    return (u16)u;
}
__device__ __forceinline__ float bf2f(u16 h) {
    return __builtin_bit_cast(float, ((u32)h) << 16);
}
__device__ __forceinline__ float sigmoidf(float x) {
    return 1.f / (1.f + __expf(-x));
}
// async global->LDS, 16B per lane; lds dest must be wave-uniform (HW adds lane*16)
__device__ __forceinline__ void gload16(const u16* g, u16* lds) {
    __builtin_amdgcn_global_load_lds(
        (const __attribute__((address_space(1))) unsigned int*)g,
        (__attribute__((address_space(3))) unsigned int*)lds, 16, 0, 0);
}

// ------- K0: weights fp32 [in][out] -> bf16 transposed, LN gain folded in ----
__global__ __launch_bounds__(256) void k_wt_all(
    const float* __restrict__ w0, const float* __restrict__ w1,
    const float* __restrict__ w2, const float* __restrict__ w3,
    const float* __restrict__ w4, const float* __restrict__ w5,
    const float* __restrict__ gin, const float* __restrict__ gout,
    u16* __restrict__ o0, u16* __restrict__ o1, u16* __restrict__ o2,
    u16* __restrict__ o3, u16* __restrict__ o4, u16* __restrict__ o5) {
    int sel = blockIdx.x >> 6;
    int idx = (blockIdx.x & 63) * 256 + threadIdx.x;
    const float* w = sel == 0 ? w0 : sel == 1 ? w1 : sel == 2 ? w2
                   : sel == 3 ? w3 : sel == 4 ? w4 : w5;
    u16* o = sel == 0 ? o0 : sel == 1 ? o1 : sel == 2 ? o2
           : sel == 3 ? o3 : sel == 4 ? o4 : o5;
    const float* g = (sel == 5) ? gout : gin;
    int co = idx >> 7, k = idx & 127;
    o[idx] = f2bf(g[k] * w[k * C + co]);
}

// ------- K0b: adjusted biases + colsum of folded w_z -------------------------
// slots 0..5: b'[c] = b[c] + sum_k b_ln[k]*W[k][c]
// slot  6   : colsum[c] = sum_k bf16round(g_out[k]*w_z[k][c])  (matches MFMA W')
__global__ __launch_bounds__(256) void k_bias(
    const float* __restrict__ w0, const float* __restrict__ w1,
    const float* __restrict__ w2, const float* __restrict__ w3,
    const float* __restrict__ w4, const float* __restrict__ w5,
    const float* __restrict__ b0, const float* __restrict__ b1,
    const float* __restrict__ b2, const float* __restrict__ b3,
    const float* __restrict__ b4, const float* __restrict__ b5,
    const float* __restrict__ vin, const float* __restrict__ vout,
    const float* __restrict__ gout,
    float* __restrict__ obias) {
    int id = blockIdx.x * 256 + threadIdx.x;   // 0..1023
    int m = id >> 7, cc = id & 127;
    if (m >= 7) return;
    if (m == 6) {
        float acc = 0.f;
#pragma unroll 4
        for (int k = 0; k < 128; ++k)
            acc += bf2f(f2bf(gout[k] * w5[k * C + cc]));
        obias[id] = acc;
        return;
    }
    const float* w = m == 0 ? w0 : m == 1 ? w1 : m == 2 ? w2
                   : m == 3 ? w3 : m == 4 ? w4 : w5;
    const float* b = m == 0 ? b0 : m == 1 ? b1 : m == 2 ? b2
                   : m == 3 ? b3 : m == 4 ? b4 : b5;
    const float* v = (m == 5) ? vout : vin;
    float acc = 0.f;
#pragma unroll 4
    for (int k = 0; k < 128; ++k) acc += v[k] * w[k * C + cc];
    obias[id] = b[cc] + acc;
}

// ------- fused: LN(z) + 5 projections in ONE sA traversal (R5, 191us) --------
__global__ __launch_bounds__(256, 2) void k_proj_fused(
    const float* __restrict__ z, const float* __restrict__ mask,
    const u16* __restrict__ wag, const u16* __restrict__ wap,
    const u16* __restrict__ wbg, const u16* __restrict__ wbp,
    const u16* __restrict__ wgg, const float* __restrict__ biasAll,
    u16* __restrict__ aT, u16* __restrict__ bT, u16* __restrict__ gate) {
    __shared__ u16 sA[64 * PK];           // 17408 B
    __shared__ u16 sT[4][2][16 * ST];     // 18432 B, per-wave x {A,B} halves
    long r0 = (long)blockIdx.x * 64;
    int tid = threadIdx.x, wave = tid >> 6, lane = tid & 63;
    int lo = lane & 15, quad = lane >> 4;

    // --- LN(z) -> sA (plain normalized, affine folded into weights/biases) ---
    {
        int rl = lane >> 2, cb = lane & 3;
        int row = wave * 16 + rl;
        const float* zr = z + (r0 + row) * C + cb * 32;
        float4 v[8];
        float s = 0.f, s2 = 0.f;
#pragma unroll
        for (int i = 0; i < 8; ++i) {
            v[i] = *(const float4*)(zr + i * 4);
            s  += v[i].x + v[i].y + v[i].z + v[i].w;
            s2 += v[i].x * v[i].x + v[i].y * v[i].y + v[i].z * v[i].z + v[i].w * v[i].w;
        }
        s += __shfl_xor(s, 1); s2 += __shfl_xor(s2, 1);
        s += __shfl_xor(s, 2); s2 += __shfl_xor(s2, 2);
        float mean = s * (1.f / 128.f);
        float rs = rsqrtf(s2 * (1.f / 128.f) - mean * mean + 1e-5f);
        u16* dst = &sA[row * PK + cb * 32];
#pragma unroll
        for (int j = 0; j < 4; ++j) {
            uint4 pk;
            pk.x = (u32)f2bf((v[2*j].x   - mean) * rs) | ((u32)f2bf((v[2*j].y   - mean) * rs) << 16);
            pk.y = (u32)f2bf((v[2*j].z   - mean) * rs) | ((u32)f2bf((v[2*j].w   - mean) * rs) << 16);
            pk.z = (u32)f2bf((v[2*j+1].x - mean) * rs) | ((u32)f2bf((v[2*j+1].y - mean) * rs) << 16);
            pk.w = (u32)f2bf((v[2*j+1].z - mean) * rs) | ((u32)f2bf((v[2*j+1].w - mean) * rs) << 16);
            *(uint4*)(dst + 8 * j) = pk;
        }
    }
    __syncthreads();

    int c0 = wave * 32;
    float msk[4][4];
#pragma unroll
    for (int mi = 0; mi < 4; ++mi)
#pragma unroll
        for (int r = 0; r < 4; ++r)
            msk[mi][r] = mask[r0 + mi * 16 + quad * 4 + r];

    auto epi = [&](const f32x4* G, const f32x4* P, float bGv, float bPv,
                   u16* sTh, u16* __restrict__ outT, int cch) {
#pragma unroll
        for (int mi = 0; mi < 4; ++mi) {
            float v0 = msk[mi][0] * sigmoidf(G[mi][0] + bGv) * (P[mi][0] + bPv);
            float v1 = msk[mi][1] * sigmoidf(G[mi][1] + bGv) * (P[mi][1] + bPv);
            float v2 = msk[mi][2] * sigmoidf(G[mi][2] + bGv) * (P[mi][2] + bPv);
            float v3 = msk[mi][3] * sigmoidf(G[mi][3] + bGv) * (P[mi][3] + bPv);
            uint2 pk;
            pk.x = (u32)f2bf(v0) | ((u32)f2bf(v1) << 16);
            pk.y = (u32)f2bf(v2) | ((u32)f2bf(v3) << 16);
            *(uint2*)(&sTh[lo * ST + mi * 16 + quad * 4]) = pk;
        }
        int cl = lane >> 2, pr = lane & 3;
        uint4 x0 = *(const uint4*)(&sTh[cl * ST + pr * 16]);
        uint4 x1 = *(const uint4*)(&sTh[cl * ST + pr * 16 + 8]);
        u16* g = outT + (long)(cch + cl) * NN + r0 + pr * 16;
        *(uint4*)(g) = x0;
        *(uint4*)(g + 8) = x1;
    };

    f32x4 gG[2][4];
#pragma unroll
    for (int nt = 0; nt < 2; ++nt)
#pragma unroll
        for (int mi = 0; mi < 4; ++mi) gG[nt][mi] = (f32x4)(0.f);

#pragma unroll
    for (int nt = 0; nt < 2; ++nt) {
        int c = c0 + nt * 16 + lo;
        bf16x8 fAG[4], fAP[4], fBG[4], fBP[4], fGG[4];
#pragma unroll
        for (int ki = 0; ki < 4; ++ki) {
            fAG[ki] = *(const bf16x8*)(wag + c * C + ki * 32 + quad * 8);
            fAP[ki] = *(const bf16x8*)(wap + c * C + ki * 32 + quad * 8);
            fBG[ki] = *(const bf16x8*)(wbg + c * C + ki * 32 + quad * 8);
            fBP[ki] = *(const bf16x8*)(wbp + c * C + ki * 32 + quad * 8);
            fGG[ki] = *(const bf16x8*)(wgg + c * C + ki * 32 + quad * 8);
        }
        f32x4 aG[4], aP[4], bG[4], bP[4];
#pragma unroll
        for (int mi = 0; mi < 4; ++mi) {
            aG[mi] = (f32x4)(0.f); aP[mi] = (f32x4)(0.f);
            bG[mi] = (f32x4)(0.f); bP[mi] = (f32x4)(0.f);
        }
#pragma unroll
        for (int mi = 0; mi < 4; ++mi)
#pragma unroll
            for (int ki = 0; ki < 4; ++ki) {
                bf16x8 av = *(const bf16x8*)(&sA[(mi * 16 + lo) * PK + ki * 32 + quad * 8]);
                aG[mi]     = __builtin_amdgcn_mfma_f32_16x16x32_bf16(av, fAG[ki], aG[mi], 0, 0, 0);
                aP[mi]     = __builtin_amdgcn_mfma_f32_16x16x32_bf16(av, fAP[ki], aP[mi], 0, 0, 0);
                bG[mi]     = __builtin_amdgcn_mfma_f32_16x16x32_bf16(av, fBG[ki], bG[mi], 0, 0, 0);
                bP[mi]     = __builtin_amdgcn_mfma_f32_16x16x32_bf16(av, fBP[ki], bP[mi], 0, 0, 0);
                gG[nt][mi] = __builtin_amdgcn_mfma_f32_16x16x32_bf16(av, fGG[ki], gG[nt][mi], 0, 0, 0);
            }
        epi(aG, aP, biasAll[c],       biasAll[128 + c], &sT[wave][0][0], aT, c0 + nt * 16);
        epi(bG, bP, biasAll[256 + c], biasAll[384 + c], &sT[wave][1][0], bT, c0 + nt * 16);
    }

    __syncthreads();   // all waves done reading sA before overwrite
    const float* bg5 = biasAll + 512;
#pragma unroll
    for (int nt = 0; nt < 2; ++nt) {
        int c = c0 + nt * 16 + lo;
        float bv = bg5[c];
#pragma unroll
        for (int mi = 0; mi < 4; ++mi)
#pragma unroll
            for (int r = 0; r < 4; ++r)
                sA[(mi * 16 + quad * 4 + r) * PK + c] = f2bf(sigmoidf(gG[nt][mi][r] + bv));
    }
    __syncthreads();
#pragma unroll
    for (int p = 0; p < 4; ++p) {
        int linear = p * 2048 + tid * 8;
        int row = linear >> 7, k = linear & 127;
        *(uint4*)(gate + (r0 + row) * C + k) = *(const uint4*)(&sA[row * PK + k]);
    }
}

// ------- K3: per-channel 512x512x512 BT-GEMM, double-buffered gload_lds ------
// x_t[c][i][j] = sum_k a_t[c][i][k] * b_t[c][j][k]
// 2-phase T3-minimum: stage tile t+1 BEFORE computing tile t; one barrier per
// phase (its implicit vmcnt drain lands the prefetch after it flew under MFMA).
__global__ __launch_bounds__(256) void k_tri(const u16* __restrict__ aT,
                                             const u16* __restrict__ bT,
                                             u16* __restrict__ xT) {
    __shared__ u16 sA[2][128 * 32];   // 2 x 8 KB
    __shared__ u16 sB[2][128 * 32];   // 2 x 8 KB
    int c = blockIdx.y;
    int i0 = (blockIdx.x >> 2) * 128, j0 = (blockIdx.x & 3) * 128;
    const u16* aBase = aT + (long)c * NN + (long)i0 * N;
    const u16* bBase = bT + (long)c * NN + (long)j0 * N;
    int tid = threadIdx.x;
    int wave = tid >> 6, lane = tid & 63, lo = lane & 15, quad = lane >> 4;
    int mq = (wave >> 1) * 64, nq = (wave & 1) * 64;
    int ld_row = lane >> 2;            // 0..15 within a 16-row chunk
    int ld_col = (lane & 3) * 8;       // u16 col, 16B per lane

    auto stage = [&](int t, int buf) {
#pragma unroll
        for (int h = 0; h < 2; ++h) {
            int ch = wave + h * 4;     // chunk 0..7 (16 rows each)
            int r = ch * 16 + ld_row;  // tile row 0..127
            gload16(aBase + (long)r * N + t * 32 + ld_col, &sA[buf][ch * 512]);
            gload16(bBase + (long)r * N + t * 32 + ld_col, &sB[buf][ch * 512]);
        }
    };

    f32x4 acc[4][4];
#pragma unroll
    for (int mi = 0; mi < 4; ++mi)
#pragma unroll
        for (int ni = 0; ni < 4; ++ni) acc[mi][ni] = (f32x4)(0.f);

    stage(0, 0);
    __syncthreads();                   // drain: buffer 0 ready
    int cur = 0;
    for (int t = 0; t < 16; ++t) {
        if (t + 1 < 16) stage(t + 1, cur ^ 1);   // prefetch flies under compute
        bf16x8 af[4], bfr[4];
#pragma unroll
        for (int mi = 0; mi < 4; ++mi)
            af[mi] = *(const bf16x8*)(&sA[cur][(mq + mi * 16 + lo) * 32 + quad * 8]);
#pragma unroll
        for (int ni = 0; ni < 4; ++ni)
            bfr[ni] = *(const bf16x8*)(&sB[cur][(nq + ni * 16 + lo) * 32 + quad * 8]);
#pragma unroll
        for (int mi = 0; mi < 4; ++mi)
#pragma unroll
            for (int ni = 0; ni < 4; ++ni)
                acc[mi][ni] = __builtin_amdgcn_mfma_f32_16x16x32_bf16(af[mi], bfr[ni], acc[mi][ni], 0, 0, 0);
        if (t + 1 < 16) {
            __syncthreads();           // drain t+1 loads + all waves done with cur
            cur ^= 1;
        }
    }
    u16* outBase = xT + (long)c * NN;
#pragma unroll
    for (int mi = 0; mi < 4; ++mi)
#pragma unroll
        for (int ni = 0; ni < 4; ++ni)
#pragma unroll
            for (int r = 0; r < 4; ++r) {
                int gi = i0 + mq + mi * 16 + quad * 4 + r;
                int gj = j0 + nq + ni * 16 + lo;
                outBase[(long)gi * N + gj] = f2bf(acc[mi][ni][r]);
            }
}

// ------- K4: raw-x GEMM + LN-in-epilogue:  rs*(x@W' - m*colsum') + bz' -------
__global__ __launch_bounds__(256) void k_out(
    const u16* __restrict__ xT, const u16* __restrict__ gate,
    const u16* __restrict__ wzT, const float* __restrict__ bz,
    const float* __restrict__ colsum,
    float* __restrict__ out) {
    __shared__ u16 sA[64 * PK];        // raw x bf16, row-major (17408 B)
    __shared__ float sRed[2][4][64];
    __shared__ float2 sMV[64];
    long r0 = (long)blockIdx.x * 64;
    int tid = threadIdx.x;
    // transpose xT (c-major) -> sA[row][c] raw bf16
#pragma unroll
    for (int p = 0; p < 4; ++p) {
        int linear = p * 2048 + tid * 8;
        int cc = linear >> 6, jr = linear & 63;
        uint4 v = *(const uint4*)(xT + (long)cc * NN + r0 + jr);
        u16* u = (u16*)&v;
#pragma unroll
        for (int e = 0; e < 8; ++e) sA[(jr + e) * PK + cc] = u[e];
    }
    __syncthreads();
    // per-row stats from raw bf16
    {
        int jr = tid & 63, part = tid >> 6;
        float s = 0.f, s2 = 0.f;
#pragma unroll
        for (int q = 0; q < 4; ++q) {
            uint4 w = *(const uint4*)(&sA[jr * PK + part * 32 + q * 8]);
            const u16* uu = (const u16*)&w;
#pragma unroll
            for (int e = 0; e < 8; ++e) { float v = bf2f(uu[e]); s += v; s2 += v * v; }
        }
        sRed[0][part][jr] = s; sRed[1][part][jr] = s2;
    }
    __syncthreads();
    if (tid < 64) {
        float S = 0.f, S2 = 0.f;
#pragma unroll
        for (int p = 0; p < 4; ++p) { S += sRed[0][p][tid]; S2 += sRed[1][p][tid]; }
        float mean = S * (1.f / 128.f);
        float var = S2 * (1.f / 128.f) - mean * mean;
        sMV[tid] = make_float2(mean, rsqrtf(var + 1e-5f));
    }
    __syncthreads();
    // GEMM on RAW x; LN applied in epilogue via (m, rs, colsum)
    int wave = tid >> 6, lane = tid & 63, lo = lane & 15, quad = lane >> 4;
    int msub = wave * 16;
    bf16x8 av[4];
#pragma unroll
    for (int ki = 0; ki < 4; ++ki)
        av[ki] = *(const bf16x8*)(&sA[(msub + lo) * PK + ki * 32 + quad * 8]);
    f32x4 acc[8];
#pragma unroll
    for (int nt = 0; nt < 8; ++nt) acc[nt] = (f32x4)(0.f);
#pragma unroll
    for (int nt = 0; nt < 8; ++nt)
#pragma unroll
        for (int ki = 0; ki < 4; ++ki) {
            bf16x8 b8 = *(const bf16x8*)(wzT + (nt * 16 + lo) * C + ki * 32 + quad * 8);
            acc[nt] = __builtin_amdgcn_mfma_f32_16x16x32_bf16(av[ki], b8, acc[nt], 0, 0, 0);
        }
    float2 mvr[4];
#pragma unroll
    for (int r = 0; r < 4; ++r) mvr[r] = sMV[msub + quad * 4 + r];
#pragma unroll
    for (int nt = 0; nt < 8; ++nt) {
        int cch = nt * 16 + lo;
        float bzv = bz[cch], csv = colsum[cch];
#pragma unroll
        for (int r = 0; r < 4; ++r) {
            int row = msub + quad * 4 + r;
            long rr = r0 + row;
            float g = bf2f(gate[rr * C + cch]);
            out[rr * C + cch] = (mvr[r].y * (acc[nt][r] - mvr[r].x * csv) + bzv) * g;
        }
    }
}

extern "C" void kernel_launch(void* const* d_in, const int* in_sizes, int n_in,
                              void* d_out, int out_size, void* d_ws, size_t ws_size,
                              hipStream_t stream) {
    const float* z       = (const float*)d_in[0];
    const float* mask    = (const float*)d_in[1];
    const float* w_ag    = (const float*)d_in[2];
    const float* b_ag    = (const float*)d_in[3];
    const float* w_ap    = (const float*)d_in[4];
    const float* b_ap    = (const float*)d_in[5];
    const float* w_bg    = (const float*)d_in[6];
    const float* b_bg    = (const float*)d_in[7];
    const float* w_bp    = (const float*)d_in[8];
    const float* b_bp    = (const float*)d_in[9];
    const float* w_g     = (const float*)d_in[10];
    const float* b_g     = (const float*)d_in[11];
    const float* w_z     = (const float*)d_in[12];
    const float* b_z     = (const float*)d_in[13];
    const float* ln_in_g = (const float*)d_in[14];
    const float* ln_in_b = (const float*)d_in[15];
    const float* ln_out_g= (const float*)d_in[16];
    const float* ln_out_b= (const float*)d_in[17];
    float* out = (float*)d_out;

    char* ws = (char*)d_ws;
    u16* a_t  = (u16*)(ws);                          // 64 MB
    u16* b_t  = (u16*)(ws + 67108864L);              // 64 MB
    u16* gate = (u16*)(ws + 134217728L);             // 64 MB
    u16* x_t  = (u16*)(ws + 201326592L);             // 64 MB
    u16* wag_t = (u16*)(ws + 268435456L);
    u16* wap_t = wag_t + 16384;
    u16* wbg_t = wag_t + 32768;
    u16* wbp_t = wag_t + 49152;
    u16* wg_t  = wag_t + 65536;
    u16* wz_t  = wag_t + 81920;
    float* biasAdj = (float*)(ws + 268435456L + 196608L);   // 7*128 fp32

    k_wt_all<<<384, 256, 0, stream>>>(w_ag, w_ap, w_bg, w_bp, w_g, w_z,
                                      ln_in_g, ln_out_g,
                                      wag_t, wap_t, wbg_t, wbp_t, wg_t, wz_t);

    k_bias<<<4, 256, 0, stream>>>(w_ag, w_ap, w_bg, w_bp, w_g, w_z,
                                  b_ag, b_ap, b_bg, b_bp, b_g, b_z,
                                  ln_in_b, ln_out_b, ln_out_g, biasAdj);

    k_proj_fused<<<NN / 64, 256, 0, stream>>>(
        z, mask, wag_t, wap_t, wbg_t, wbp_t, wg_t, biasAdj,
        a_t, b_t, gate);

    k_tri<<<dim3(16, 128), 256, 0, stream>>>(a_t, b_t, x_t);

    k_out<<<NN / 64, 256, 0, stream>>>(x_t, gate, wz_t, biasAdj + 640,
                                       biasAdj + 768, out);
}